// Round 5
// baseline (299.241 us; speedup 1.0000x reference)
//
#include <hip/hip_runtime.h>
#include <math.h>

// ---------------------------------------------------------------------------
// Problem: B=65536 samples.
//   pre  = relu(X[B,784] @ W1[784,4] + b1)          <- HBM-bound (~196 MiB read)
//   q    = 4-qubit circuit(pre angles; qw[2,4])     <- tiny, register state
//   post = relu(q @ W2[4,32] + b2)
//   out  = softmax(post @ W3[32,2] + b3)            -> [B,2] fp32
//
// R5: SINGLE fused kernel, thread-per-sample.
//   - R3 (8-way LDS conflict) == R4 (reg-W, no LDS) in total time -> gemv was
//     never LDS-bound; suspect the wave-per-sample reduce/launch structure.
//   - Each thread streams its own row (own 64B lines, fully consumed ->
//     HBM traffic unchanged), accumulates 4 dots in registers: NO shuffles,
//     NO second dispatch, NO pre round-trip.
//   - W1 staged once in LDS, read as 64-lane broadcasts (conflict-free,
//     lgkm counter) -- independent of the vmcnt X pipeline.
//   - X: depth-2 rotating pipeline (8 loads = 8 KB/wave in flight;
//     4 waves/CU -> 32 KB >> 9.2 KB needed for 6.3 TB/s).
// ---------------------------------------------------------------------------

constexpr int ROW   = 784;   // floats per input row
constexpr int ROW4  = 196;   // float4 per input row (= 49 chunks of 4)

__device__ __forceinline__ void apply_rx(float (&sr)[16], float (&si)[16],
                                         int mask, float c, float s)
{
    #pragma unroll
    for (int i = 0; i < 16; i++) {
        if (!(i & mask)) {
            int j = i | mask;
            float x0 = sr[i], y0 = si[i], x1 = sr[j], y1 = si[j];
            sr[i] = fmaf(c, x0,  s * y1);   // Re(c*s0 - i*s*s1)
            si[i] = fmaf(c, y0, -s * x1);   // Im(c*s0 - i*s*s1)
            sr[j] = fmaf(c, x1,  s * y0);   // Re(-i*s*s0 + c*s1)
            si[j] = fmaf(c, y1, -s * x0);   // Im(-i*s*s0 + c*s1)
        }
    }
}

__device__ __forceinline__ void apply_cnot(float (&sr)[16], float (&si)[16],
                                           int cmask, int tmask)
{
    #pragma unroll
    for (int i = 0; i < 16; i++) {
        if ((i & cmask) && !(i & tmask)) {
            int j = i | tmask;
            float tr = sr[i]; sr[i] = sr[j]; sr[j] = tr;
            float ti = si[i]; si[i] = si[j]; si[j] = ti;
        }
    }
}

__global__ __launch_bounds__(256) void fused_model_kernel(
    const float* __restrict__ X,    // [B,784]
    const float* __restrict__ W1,   // [784,4]
    const float* __restrict__ b1,   // [4]
    const float* __restrict__ qw,   // [2,4]
    const float* __restrict__ W2,   // [4,32]
    const float* __restrict__ b2,   // [32]
    const float* __restrict__ W3,   // [32,2]
    const float* __restrict__ b3,   // [2]
    float* __restrict__ out,        // [B,2]
    int B)
{
    // ---- Stage W1 into LDS (plain layout; all later reads are broadcasts) ----
    __shared__ float4 w_lds[ROW];   // 784 float4 = 12544 B
    const float4* W1f4 = reinterpret_cast<const float4*>(W1);
    for (int g = threadIdx.x; g < ROW; g += 256) w_lds[g] = W1f4[g];
    __syncthreads();

    const int s = blockIdx.x * 256 + threadIdx.x;
    if (s >= B) return;

    const float4* xr = reinterpret_cast<const float4*>(X) + (size_t)s * ROW4;

    // ---- GEMV: 49 chunks of 4 float4 (one 64B line per chunk per lane) ----
    float a0 = 0.f, a1 = 0.f, a2 = 0.f, a3 = 0.f;

    float4 A0 = xr[0], A1 = xr[1], A2 = xr[2], A3 = xr[3];   // chunk 0
    float4 B0 = xr[4], B1 = xr[5], B2 = xr[6], B3 = xr[7];   // chunk 1

    #pragma unroll 3
    for (int c = 0; c < 49; c++) {
        const int nx = (c < 47) ? ((c + 2) << 2) : 0;        // prefetch c+2
        float4 C0 = xr[nx], C1 = xr[nx + 1], C2 = xr[nx + 2], C3 = xr[nx + 3];

        const float4* wl = &w_lds[c << 4];  // W1 rows 16c..16c+15 (broadcast)
        float4 w;
        w = wl[0];  a0=fmaf(A0.x,w.x,a0); a1=fmaf(A0.x,w.y,a1); a2=fmaf(A0.x,w.z,a2); a3=fmaf(A0.x,w.w,a3);
        w = wl[1];  a0=fmaf(A0.y,w.x,a0); a1=fmaf(A0.y,w.y,a1); a2=fmaf(A0.y,w.z,a2); a3=fmaf(A0.y,w.w,a3);
        w = wl[2];  a0=fmaf(A0.z,w.x,a0); a1=fmaf(A0.z,w.y,a1); a2=fmaf(A0.z,w.z,a2); a3=fmaf(A0.z,w.w,a3);
        w = wl[3];  a0=fmaf(A0.w,w.x,a0); a1=fmaf(A0.w,w.y,a1); a2=fmaf(A0.w,w.z,a2); a3=fmaf(A0.w,w.w,a3);
        w = wl[4];  a0=fmaf(A1.x,w.x,a0); a1=fmaf(A1.x,w.y,a1); a2=fmaf(A1.x,w.z,a2); a3=fmaf(A1.x,w.w,a3);
        w = wl[5];  a0=fmaf(A1.y,w.x,a0); a1=fmaf(A1.y,w.y,a1); a2=fmaf(A1.y,w.z,a2); a3=fmaf(A1.y,w.w,a3);
        w = wl[6];  a0=fmaf(A1.z,w.x,a0); a1=fmaf(A1.z,w.y,a1); a2=fmaf(A1.z,w.z,a2); a3=fmaf(A1.z,w.w,a3);
        w = wl[7];  a0=fmaf(A1.w,w.x,a0); a1=fmaf(A1.w,w.y,a1); a2=fmaf(A1.w,w.z,a2); a3=fmaf(A1.w,w.w,a3);
        w = wl[8];  a0=fmaf(A2.x,w.x,a0); a1=fmaf(A2.x,w.y,a1); a2=fmaf(A2.x,w.z,a2); a3=fmaf(A2.x,w.w,a3);
        w = wl[9];  a0=fmaf(A2.y,w.x,a0); a1=fmaf(A2.y,w.y,a1); a2=fmaf(A2.y,w.z,a2); a3=fmaf(A2.y,w.w,a3);
        w = wl[10]; a0=fmaf(A2.z,w.x,a0); a1=fmaf(A2.z,w.y,a1); a2=fmaf(A2.z,w.z,a2); a3=fmaf(A2.z,w.w,a3);
        w = wl[11]; a0=fmaf(A2.w,w.x,a0); a1=fmaf(A2.w,w.y,a1); a2=fmaf(A2.w,w.z,a2); a3=fmaf(A2.w,w.w,a3);
        w = wl[12]; a0=fmaf(A3.x,w.x,a0); a1=fmaf(A3.x,w.y,a1); a2=fmaf(A3.x,w.z,a2); a3=fmaf(A3.x,w.w,a3);
        w = wl[13]; a0=fmaf(A3.y,w.x,a0); a1=fmaf(A3.y,w.y,a1); a2=fmaf(A3.y,w.z,a2); a3=fmaf(A3.y,w.w,a3);
        w = wl[14]; a0=fmaf(A3.z,w.x,a0); a1=fmaf(A3.z,w.y,a1); a2=fmaf(A3.z,w.z,a2); a3=fmaf(A3.z,w.w,a3);
        w = wl[15]; a0=fmaf(A3.w,w.x,a0); a1=fmaf(A3.w,w.y,a1); a2=fmaf(A3.w,w.z,a2); a3=fmaf(A3.w,w.w,a3);

        A0 = B0; A1 = B1; A2 = B2; A3 = B3;
        B0 = C0; B1 = C1; B2 = C2; B3 = C3;
    }

    // ---- bias + relu -> angles ----
    const float ang0 = fmaxf(a0 + b1[0], 0.f);
    const float ang1 = fmaxf(a1 + b1[1], 0.f);
    const float ang2 = fmaxf(a2 + b1[2], 0.f);
    const float ang3 = fmaxf(a3 + b1[3], 0.f);

    // ---- quantum circuit: wire q <-> bit (3-q) (wire 0 = MSB) ----
    float sr[16], si[16];
    #pragma unroll
    for (int i = 0; i < 16; i++) { sr[i] = 0.f; si[i] = 0.f; }
    sr[0] = 1.f;

    {
        float c, sn;
        __sincosf(ang0 * 0.5f, &sn, &c); apply_rx(sr, si, 8, c, sn);
        __sincosf(ang1 * 0.5f, &sn, &c); apply_rx(sr, si, 4, c, sn);
        __sincosf(ang2 * 0.5f, &sn, &c); apply_rx(sr, si, 2, c, sn);
        __sincosf(ang3 * 0.5f, &sn, &c); apply_rx(sr, si, 1, c, sn);
    }

    #pragma unroll
    for (int l = 0; l < 2; l++) {
        #pragma unroll
        for (int q = 0; q < 4; q++) {
            float c, sn;
            __sincosf(qw[l * 4 + q] * 0.5f, &sn, &c);
            apply_rx(sr, si, 8 >> q, c, sn);
        }
        apply_cnot(sr, si, 8, 4);
        apply_cnot(sr, si, 4, 2);
        apply_cnot(sr, si, 2, 1);
        apply_cnot(sr, si, 1, 8);
    }

    // ---- <Z_q> ----
    float z0 = 0.f, z1 = 0.f, z2 = 0.f, z3 = 0.f;
    #pragma unroll
    for (int i = 0; i < 16; i++) {
        float p = fmaf(sr[i], sr[i], si[i] * si[i]);
        z0 += (i & 8) ? -p : p;
        z1 += (i & 4) ? -p : p;
        z2 += (i & 2) ? -p : p;
        z3 += (i & 1) ? -p : p;
    }
    z0 = (z0 == z0) ? z0 : 0.f;
    z1 = (z1 == z1) ? z1 : 0.f;
    z2 = (z2 == z2) ? z2 : 0.f;
    z3 = (z3 == z3) ? z3 : 0.f;

    // ---- post = relu(z @ W2 + b2); logits = post @ W3 + b3; softmax ----
    float l0 = b3[0], l1 = b3[1];
    #pragma unroll
    for (int k = 0; k < 32; k++) {
        float v = b2[k];
        v = fmaf(z0, W2[k],      v);
        v = fmaf(z1, W2[32 + k], v);
        v = fmaf(z2, W2[64 + k], v);
        v = fmaf(z3, W2[96 + k], v);
        v = fmaxf(v, 0.f);
        l0 = fmaf(v, W3[2 * k],     l0);
        l1 = fmaf(v, W3[2 * k + 1], l1);
    }

    float m  = fmaxf(l0, l1);
    float e0 = __expf(l0 - m), e1 = __expf(l1 - m);
    float inv = 1.f / (e0 + e1);
    reinterpret_cast<float2*>(out)[s] = make_float2(e0 * inv, e1 * inv);
}

// ---------------------------------------------------------------------------
extern "C" void kernel_launch(void* const* d_in, const int* in_sizes, int n_in,
                              void* d_out, int out_size, void* d_ws, size_t ws_size,
                              hipStream_t stream)
{
    const float* X  = (const float*)d_in[0];  // [B,28,28]
    const float* W1 = (const float*)d_in[1];  // [784,4]
    const float* b1 = (const float*)d_in[2];  // [4]
    const float* qw = (const float*)d_in[3];  // [2,4]
    const float* W2 = (const float*)d_in[4];  // [4,32]
    const float* b2 = (const float*)d_in[5];  // [32]
    const float* W3 = (const float*)d_in[6];  // [32,2]
    const float* b3 = (const float*)d_in[7];  // [2]

    const int B = in_sizes[0] / ROW;

    fused_model_kernel<<<(B + 255) / 256, 256, 0, stream>>>(
        X, W1, b1, qw, W2, b2, W3, b3, (float*)d_out, B);
}